// Round 19
// baseline (229.502 us; speedup 1.0000x reference)
//
#include <hip/hip_runtime.h>

// Correlation: out[b,(p+4)*9+(q+4),y,x] = (1/128) * sum_c A[b,c,y,x]*B[b,c,y+p,x+q]
// A,B = (8,128,128,128) fp32; out = (8,81,128,128) fp32. B zero-padded.
//
// R10 (resubmit x2 — R17/R18 benches died in infra, kernel never ran):
// R7's 16-channel geometry, R9's runtime loop. History:
//  - R5 (4-ch bodies, 2-ahead prefetch, draining barrier): 92.7us. Drain
//    negates the 2nd prefetch; ~650cy A-plane miss exposed per body.
//  - R6 (non-draining barrier): FETCH +45MB, 110us — drain's phase-lock is
//    what gives L2 the 9x B reuse. Keep draining __syncthreads.
//  - R7/R8 (16/8-ch bodies, #pragma unroll on k-loop): full unroll let the
//    scheduler hoist all superchunks' loads -> VGPR blowup -> staging spilled
//    to scratch (VGPR=84, WRITE 0.86-1.37GB, 455-650us).
//  - R9 (8-ch, runtime loop): spill gone (VGPR 56, WRITE 41.5MB) but 99.7us:
//    220cy body < 650cy latency -> vmcnt wait at STAGES still exposes ~400cy.
// R10: 16-ch superchunks (8 bodies, ~600cy dot2 issue per body >= latency) +
// `unroll(disable)` so only ONE staging set is live (12 f4 = 48 VGPR; total
// ~125 < 170 cap, no spill). Loads issued at body top are ~600cy old when
// STAGES consumes them; the draining barrier is then nearly free.
// LDS 35.8KB (4 blocks/CU). f16 pair-packing + v_dot2_f32_f16, 192 threads,
// grid 3072, batch->XCD affinity in low blockIdx bits.

typedef __fp16 h2 __attribute__((ext_vector_type(2)));

#define BW2 144   // padded B row in h2 units; j = x+4, valid j in [0,136), pad to 144

#if __has_builtin(__builtin_amdgcn_fdot2)
  #define FDOT2(a, b, c) __builtin_amdgcn_fdot2((a), (b), (c), false)
#else
  static __device__ inline float FDOT2(h2 a, h2 b, float c) {
      return c + (float)a.x * (float)b.x + (float)a.y * (float)b.y;
  }
#endif

static __device__ inline float pk2f(float lo, float hi) {
    h2 v = __builtin_amdgcn_cvt_pkrtz(lo, hi);   // (f16(lo), f16(hi)) packed
    return __builtin_bit_cast(float, v);
}
static __device__ inline h2 f2h2(float f) { return __builtin_bit_cast(h2, f); }

__global__ __launch_bounds__(192, 3)
void corr_kernel(const float* __restrict__ A, const float* __restrict__ B,
                 float* __restrict__ out)
{
    const int bidx = blockIdx.x;
    const int bb = bidx & 7;          // batch -> XCD affinity
    const int t2 = bidx >> 3;
    const int y  = t2 & 127;
    const int pg = t2 >> 7;           // p-group 0..2

    const int tid  = threadIdx.x;     // 0..191
    const int wave = tid >> 6;        // 0..2
    const int lane = tid & 63;
    const int cs   = lane >> 5;       // pair-select (even/odd pair slot)
    const int x0   = (lane & 31) << 2;
    const int pr   = pg * 3 + wave;   // 0..8 -> p = pr-4

    // 16 channels (8 packed pairs) per buffer
    __shared__ h2 a_s[2][8][128];      // [buf][pair][x]          8 KB
    __shared__ h2 b_s[2][3][8][BW2];   // [buf][row][pair][j]     27.6 KB

    float acc[9][4];
    #pragma unroll
    for (int q = 0; q < 9; ++q)
        #pragma unroll
        for (int i = 0; i < 4; ++i) acc[q][i] = 0.f;

    const long plane = 128L * 128L;
    const float* Abase = A + (long)bb * 128 * plane + (long)y * 128;
    const float* Bbase = B + (long)bb * 128 * plane;

    // ---- staging unit descriptors (computed once) ----
    // B: 3 rows x 8 pairs x 32 col-quads = 768 units; thread t owns u = t+192*i.
    const float* Bu[4]; int Boff[4]; bool Bv[4];
    #pragma unroll
    for (int i = 0; i < 4; ++i) {
        const int u   = tid + 192 * i;
        const int r   = u >> 8;          // row slot 0..2
        const int rem = u & 255;
        const int pru = rem >> 5;        // pair 0..7
        const int col = rem & 31;        // col quad
        const int bys = y + pg * 3 + r - 4;
        Bv[i]  = (unsigned)bys < 128u;
        Bu[i]  = Bbase + (long)(Bv[i] ? bys : 0) * 128 + col * 4
                       + (long)(2 * pru) * plane;
        Boff[i] = (r * 8 + pru) * BW2 + 4 + col * 4;   // h2 index into b_s[buf]
    }
    // A: 8 pairs x 32 col-quads = 256 units; threads 0..127 own u = t, t+128.
    const bool aact = tid < 128;
    const float* Au[2]; int Aoff[2];
    #pragma unroll
    for (int i = 0; i < 2; ++i) {
        const int u   = (tid & 127) + 128 * i;
        const int pru = u >> 5;
        const int col = u & 31;
        Au[i]  = Abase + col * 4 + (long)(2 * pru) * plane;
        Aoff[i] = pru * 128 + col * 4;                 // h2 index into a_s[buf]
    }

    // single staging register set: 12 float4 = 48 VGPR (fits; R7's spill was
    // caused by the unrolled loop keeping 7 sets live, not by set size)
    float4 rb[4][2], ra[2][2];

#define LOADS(SC) do {                                                   \
    const long choff_ = (long)((SC) << 4) * plane;                       \
    _Pragma("unroll")                                                    \
    for (int i = 0; i < 2; ++i) if (aact) {                              \
        ra[i][0] = *(const float4*)(Au[i] + choff_);                     \
        ra[i][1] = *(const float4*)(Au[i] + choff_ + plane);             \
    }                                                                    \
    _Pragma("unroll")                                                    \
    for (int i = 0; i < 4; ++i) if (Bv[i]) {                             \
        rb[i][0] = *(const float4*)(Bu[i] + choff_);                     \
        rb[i][1] = *(const float4*)(Bu[i] + choff_ + plane);             \
    }                                                                    \
} while (0)

#define STAGES(BUF) do {                                                 \
    h2* bb_ = &b_s[(BUF)][0][0][0];                                      \
    _Pragma("unroll")                                                    \
    for (int i = 0; i < 4; ++i) if (Bv[i]) {                             \
        float4 w_;                                                       \
        w_.x = pk2f(rb[i][0].x, rb[i][1].x);                             \
        w_.y = pk2f(rb[i][0].y, rb[i][1].y);                             \
        w_.z = pk2f(rb[i][0].z, rb[i][1].z);                             \
        w_.w = pk2f(rb[i][0].w, rb[i][1].w);                             \
        *(float4*)(bb_ + Boff[i]) = w_;                                  \
    }                                                                    \
    if (aact) {                                                          \
        h2* aa_ = &a_s[(BUF)][0][0];                                     \
        _Pragma("unroll")                                                \
        for (int i = 0; i < 2; ++i) {                                    \
            float4 w_;                                                   \
            w_.x = pk2f(ra[i][0].x, ra[i][1].x);                         \
            w_.y = pk2f(ra[i][0].y, ra[i][1].y);                         \
            w_.z = pk2f(ra[i][0].z, ra[i][1].z);                         \
            w_.w = pk2f(ra[i][0].w, ra[i][1].w);                         \
            *(float4*)(aa_ + Aoff[i]) = w_;                              \
        }                                                                \
    }                                                                    \
} while (0)

#define COMPUTE(BUF) do {                                                        \
    _Pragma("unroll")                                                            \
    for (int pp = 0; pp < 4; ++pp) {                                             \
        const int pair_ = (pp << 1) | cs;                                        \
        const float4 av  = *(const float4*)&a_s[(BUF)][pair_][x0];               \
        const float4 b0v = *(const float4*)&b_s[(BUF)][wave][pair_][x0];         \
        const float4 b1v = *(const float4*)&b_s[(BUF)][wave][pair_][x0 + 4];     \
        const float4 b2v = *(const float4*)&b_s[(BUF)][wave][pair_][x0 + 8];     \
        const h2 a2[4] = { f2h2(av.x), f2h2(av.y), f2h2(av.z), f2h2(av.w) };     \
        const h2 w[12] = { f2h2(b0v.x), f2h2(b0v.y), f2h2(b0v.z), f2h2(b0v.w),   \
                           f2h2(b1v.x), f2h2(b1v.y), f2h2(b1v.z), f2h2(b1v.w),   \
                           f2h2(b2v.x), f2h2(b2v.y), f2h2(b2v.z), f2h2(b2v.w) }; \
        _Pragma("unroll")                                                        \
        for (int q = 0; q < 9; ++q)                                              \
            _Pragma("unroll")                                                    \
            for (int i = 0; i < 4; ++i)                                          \
                acc[q][i] = FDOT2(a2[i], w[q + i], acc[q][i]);                   \
    }                                                                            \
} while (0)

    // prologue: issue super-chunk 0 loads, zero LDS pads under their latency
    LOADS(0);
    {
        float4* pa = (float4*)&a_s[0][0][0];
        const int na = 2 * 8 * 128 / 4;          // 512 float4
        for (int i = tid; i < na; i += 192) pa[i] = make_float4(0.f, 0.f, 0.f, 0.f);
        float4* pb = (float4*)&b_s[0][0][0][0];
        const int nb = 2 * 3 * 8 * BW2 / 4;      // 1728 float4
        for (int i = tid; i < nb; i += 192) pb[i] = make_float4(0.f, 0.f, 0.f, 0.f);
    }
    __syncthreads();        // zero-init visible
    STAGES(0);
    __syncthreads();        // buf0 ready

    // 8 super-chunks of 16 channels — RUNTIME loop (R7/R8's full unroll kept
    // many staging sets live -> scratch spill; R9 proved unroll(disable)
    // keeps one set and honest VGPRs)
    #pragma clang loop unroll(disable)
    for (int k = 0; k < 7; ++k) {
        const int buf = k & 1;
        LOADS(k + 1);           // issue next super-chunk's loads (~600cy early)
        COMPUTE(buf);           // ~600cy of dot2 issue hides the load latency
        STAGES(buf ^ 1);        // counted vmcnt wait: loads mostly complete
        __syncthreads();        // drain (cheap now) + phase-lock for B L2-reuse
    }
    COMPUTE(1);                 // k = 7

#undef COMPUTE
#undef STAGES
#undef LOADS

    // combine pair-split halves (lane L += lane L+32)
    #pragma unroll
    for (int q = 0; q < 9; ++q)
        #pragma unroll
        for (int i = 0; i < 4; ++i)
            acc[q][i] += __shfl_down(acc[q][i], 32);

    if (cs == 0) {
        const float scale = 1.0f / 128.0f;
        float* obase = out + (((long)bb * 81 + (long)pr * 9) * 128 + y) * 128 + x0;
        #pragma unroll
        for (int q = 0; q < 9; ++q) {
            const float4 v = make_float4(acc[q][0] * scale, acc[q][1] * scale,
                                         acc[q][2] * scale, acc[q][3] * scale);
            *(float4*)(obase + (long)q * plane) = v;
        }
    }
}

extern "C" void kernel_launch(void* const* d_in, const int* in_sizes, int n_in,
                              void* d_out, int out_size, void* d_ws, size_t ws_size,
                              hipStream_t stream) {
    const float* a = (const float*)d_in[0];
    const float* b = (const float*)d_in[1];
    float* out = (float*)d_out;
    // grid: 8 batches * 128 y * 3 p-groups = 3072 blocks; 192 threads (3 waves)
    hipLaunchKernelGGL(corr_kernel, dim3(3072), dim3(192), 0, stream, a, b, out);
}

// Round 20
// 224.347 us; speedup vs baseline: 1.0230x; 1.0230x over previous
//
#include <hip/hip_runtime.h>

// Correlation: out[b,(p+4)*9+(q+4),y,x] = (1/128) * sum_c A[b,c,y,x]*B[b,c,y+p,x+q]
// A,B = (8,128,128,128) fp32; out = (8,81,128,128) fp32. B zero-padded.
//
// R11: pin waves-per-EU to stop the compiler's spill-for-occupancy. History:
//  - R5 (4-ch, draining barrier): 92.7us, ~650cy miss exposed per body.
//  - R6 (no drain): FETCH +45MB — drain's phase-lock gives L2 the 9x B reuse.
//  - R7/R8 (unrolled k-loop): scheduler kept many staging sets live -> spill.
//  - R9 (8-ch, runtime loop): clean (VGPR 56) but 220cy body < latency: 99.7us.
//  - R10 (16-ch, runtime loop): STILL VGPR=84 + 16MB spill — the AMDGPU
//    scheduler capped regs at 512/6 to chase 6 waves/EU, but LDS (35.8KB)
//    caps at 4 blocks/CU = 3 waves/EU, so the spill bought nothing. 125us.
// R11 = R10 + amdgpu_waves_per_eu(3,3) (register budget 512/3=170, no
// heuristic spill) + saddr addressing (uniform char* base + u32 per-lane
// offsets: 1 VGPR/address, all offsets < 8.4MB). Est ~125 VGPR < 170.
// 16-ch superchunks, 8 bodies, ~600cy dot2 issue/body >= ~650cy latency:
// the per-barrier miss finally amortized. LDS 35.8KB. f16 pair-packing +
// v_dot2_f32_f16, 192 threads, grid 3072, batch->XCD affinity.

typedef __fp16 h2 __attribute__((ext_vector_type(2)));

#define BW2 144   // padded B row in h2 units; j = x+4, valid j in [0,136), pad to 144
#define PLANE_B 65536u   // one channel plane in bytes (128*128*4)

#if __has_builtin(__builtin_amdgcn_fdot2)
  #define FDOT2(a, b, c) __builtin_amdgcn_fdot2((a), (b), (c), false)
#else
  static __device__ inline float FDOT2(h2 a, h2 b, float c) {
      return c + (float)a.x * (float)b.x + (float)a.y * (float)b.y;
  }
#endif

static __device__ inline float pk2f(float lo, float hi) {
    h2 v = __builtin_amdgcn_cvt_pkrtz(lo, hi);   // (f16(lo), f16(hi)) packed
    return __builtin_bit_cast(float, v);
}
static __device__ inline h2 f2h2(float f) { return __builtin_bit_cast(h2, f); }

__global__ __launch_bounds__(192)
__attribute__((amdgpu_waves_per_eu(3, 3)))
void corr_kernel(const float* __restrict__ A, const float* __restrict__ B,
                 float* __restrict__ out)
{
    const int bidx = blockIdx.x;
    const int bb = bidx & 7;          // batch -> XCD affinity
    const int t2 = bidx >> 3;
    const int y  = t2 & 127;
    const int pg = t2 >> 7;           // p-group 0..2

    const int tid  = threadIdx.x;     // 0..191
    const int wave = tid >> 6;        // 0..2
    const int lane = tid & 63;
    const int cs   = lane >> 5;       // pair-select (even/odd pair slot)
    const int x0   = (lane & 31) << 2;
    const int pr   = pg * 3 + wave;   // 0..8 -> p = pr-4

    // 16 channels (8 packed pairs) per buffer
    __shared__ h2 a_s[2][8][128];      // [buf][pair][x]          8 KB
    __shared__ h2 b_s[2][3][8][BW2];   // [buf][row][pair][j]     27.6 KB

    float acc[9][4];
    #pragma unroll
    for (int q = 0; q < 9; ++q)
        #pragma unroll
        for (int i = 0; i < 4; ++i) acc[q][i] = 0.f;

    const long plane = 128L * 128L;
    // uniform (per-block) byte bases -> saddr-form global loads:
    // 64-bit base lives in SGPRs, per-lane address is ONE u32 VGPR.
    const char* Ab = (const char*)(A + (long)bb * 128 * plane);
    const char* Bb = (const char*)(B + (long)bb * 128 * plane);

    // ---- staging unit descriptors (computed once; u32 byte offsets) ----
    // B: 3 rows x 8 pairs x 32 col-quads = 768 units; thread t owns u = t+192*i.
    unsigned BoffG[4]; int BoffL[4]; bool Bv[4];
    #pragma unroll
    for (int i = 0; i < 4; ++i) {
        const int u   = tid + 192 * i;
        const int r   = u >> 8;          // row slot 0..2
        const int rem = u & 255;
        const int pru = rem >> 5;        // pair 0..7
        const int col = rem & 31;        // col quad
        const int bys = y + pg * 3 + r - 4;
        Bv[i]    = (unsigned)bys < 128u;
        BoffG[i] = (unsigned)(((Bv[i] ? bys : 0) * 128 + col * 4) * 4)
                 + (unsigned)(2 * pru) * PLANE_B;
        BoffL[i] = (r * 8 + pru) * BW2 + 4 + col * 4;   // h2 index into b_s[buf]
    }
    // A: 8 pairs x 32 col-quads = 256 units; threads 0..127 own u = t, t+128.
    const bool aact = tid < 128;
    unsigned AoffG[2]; int AoffL[2];
    #pragma unroll
    for (int i = 0; i < 2; ++i) {
        const int u   = (tid & 127) + 128 * i;
        const int pru = u >> 5;
        const int col = u & 31;
        AoffG[i] = (unsigned)((y * 128 + col * 4) * 4)
                 + (unsigned)(2 * pru) * PLANE_B;
        AoffL[i] = pru * 128 + col * 4;                 // h2 index into a_s[buf]
    }

    // single staging register set: 12 float4 = 48 VGPR
    float4 rb[4][2], ra[2][2];

#define LOADS(SC) do {                                                    \
    const unsigned ch_ = (unsigned)((SC) << 4) * PLANE_B;                 \
    _Pragma("unroll")                                                     \
    for (int i = 0; i < 2; ++i) if (aact) {                               \
        ra[i][0] = *(const float4*)(Ab + (AoffG[i] + ch_));               \
        ra[i][1] = *(const float4*)(Ab + (AoffG[i] + ch_ + PLANE_B));     \
    }                                                                     \
    _Pragma("unroll")                                                     \
    for (int i = 0; i < 4; ++i) if (Bv[i]) {                              \
        rb[i][0] = *(const float4*)(Bb + (BoffG[i] + ch_));               \
        rb[i][1] = *(const float4*)(Bb + (BoffG[i] + ch_ + PLANE_B));     \
    }                                                                     \
} while (0)

#define STAGES(BUF) do {                                                 \
    h2* bb_ = &b_s[(BUF)][0][0][0];                                      \
    _Pragma("unroll")                                                    \
    for (int i = 0; i < 4; ++i) if (Bv[i]) {                             \
        float4 w_;                                                       \
        w_.x = pk2f(rb[i][0].x, rb[i][1].x);                             \
        w_.y = pk2f(rb[i][0].y, rb[i][1].y);                             \
        w_.z = pk2f(rb[i][0].z, rb[i][1].z);                             \
        w_.w = pk2f(rb[i][0].w, rb[i][1].w);                             \
        *(float4*)(bb_ + BoffL[i]) = w_;                                 \
    }                                                                    \
    if (aact) {                                                          \
        h2* aa_ = &a_s[(BUF)][0][0];                                     \
        _Pragma("unroll")                                                \
        for (int i = 0; i < 2; ++i) {                                    \
            float4 w_;                                                   \
            w_.x = pk2f(ra[i][0].x, ra[i][1].x);                         \
            w_.y = pk2f(ra[i][0].y, ra[i][1].y);                         \
            w_.z = pk2f(ra[i][0].z, ra[i][1].z);                         \
            w_.w = pk2f(ra[i][0].w, ra[i][1].w);                         \
            *(float4*)(aa_ + AoffL[i]) = w_;                             \
        }                                                                \
    }                                                                    \
} while (0)

#define COMPUTE(BUF) do {                                                        \
    _Pragma("unroll")                                                            \
    for (int pp = 0; pp < 4; ++pp) {                                             \
        const int pair_ = (pp << 1) | cs;                                        \
        const float4 av  = *(const float4*)&a_s[(BUF)][pair_][x0];               \
        const float4 b0v = *(const float4*)&b_s[(BUF)][wave][pair_][x0];         \
        const float4 b1v = *(const float4*)&b_s[(BUF)][wave][pair_][x0 + 4];     \
        const float4 b2v = *(const float4*)&b_s[(BUF)][wave][pair_][x0 + 8];     \
        const h2 a2[4] = { f2h2(av.x), f2h2(av.y), f2h2(av.z), f2h2(av.w) };     \
        const h2 w[12] = { f2h2(b0v.x), f2h2(b0v.y), f2h2(b0v.z), f2h2(b0v.w),   \
                           f2h2(b1v.x), f2h2(b1v.y), f2h2(b1v.z), f2h2(b1v.w),   \
                           f2h2(b2v.x), f2h2(b2v.y), f2h2(b2v.z), f2h2(b2v.w) }; \
        _Pragma("unroll")                                                        \
        for (int q = 0; q < 9; ++q)                                              \
            _Pragma("unroll")                                                    \
            for (int i = 0; i < 4; ++i)                                          \
                acc[q][i] = FDOT2(a2[i], w[q + i], acc[q][i]);                   \
    }                                                                            \
} while (0)

    // prologue: issue super-chunk 0 loads, zero LDS pads under their latency
    LOADS(0);
    {
        float4* pa = (float4*)&a_s[0][0][0];
        const int na = 2 * 8 * 128 / 4;          // 512 float4
        for (int i = tid; i < na; i += 192) pa[i] = make_float4(0.f, 0.f, 0.f, 0.f);
        float4* pb = (float4*)&b_s[0][0][0][0];
        const int nb = 2 * 3 * 8 * BW2 / 4;      // 1728 float4
        for (int i = tid; i < nb; i += 192) pb[i] = make_float4(0.f, 0.f, 0.f, 0.f);
    }
    __syncthreads();        // zero-init visible
    STAGES(0);
    __syncthreads();        // buf0 ready

    // 8 super-chunks of 16 channels — RUNTIME loop (R7/R8's full unroll kept
    // many staging sets live -> scratch spill; R9/R10 proved unroll(disable)
    // alone is not enough — waves_per_eu(3,3) stops the heuristic spill)
    #pragma clang loop unroll(disable)
    for (int k = 0; k < 7; ++k) {
        const int buf = k & 1;
        LOADS(k + 1);           // issue next super-chunk's loads (~600cy early)
        COMPUTE(buf);           // ~600cy of dot2 issue hides the load latency
        STAGES(buf ^ 1);        // counted vmcnt wait: loads mostly complete
        __syncthreads();        // drain (cheap now) + phase-lock for B L2-reuse
    }
    COMPUTE(1);                 // k = 7

#undef COMPUTE
#undef STAGES
#undef LOADS

    // combine pair-split halves (lane L += lane L+32)
    #pragma unroll
    for (int q = 0; q < 9; ++q)
        #pragma unroll
        for (int i = 0; i < 4; ++i)
            acc[q][i] += __shfl_down(acc[q][i], 32);

    if (cs == 0) {
        const float scale = 1.0f / 128.0f;
        float* obase = out + (((long)bb * 81 + (long)pr * 9) * 128 + y) * 128 + x0;
        #pragma unroll
        for (int q = 0; q < 9; ++q) {
            const float4 v = make_float4(acc[q][0] * scale, acc[q][1] * scale,
                                         acc[q][2] * scale, acc[q][3] * scale);
            *(float4*)(obase + (long)q * plane) = v;
        }
    }
}

extern "C" void kernel_launch(void* const* d_in, const int* in_sizes, int n_in,
                              void* d_out, int out_size, void* d_ws, size_t ws_size,
                              hipStream_t stream) {
    const float* a = (const float*)d_in[0];
    const float* b = (const float*)d_in[1];
    float* out = (float*)d_out;
    // grid: 8 batches * 128 y * 3 p-groups = 3072 blocks; 192 threads (3 waves)
    hipLaunchKernelGGL(corr_kernel, dim3(3072), dim3(192), 0, stream, a, b, out);
}